// Round 9
// baseline (374.047 us; speedup 1.0000x reference)
//
#include <hip/hip_runtime.h>
#include <math.h>

#define C_CH 512
#define L_SEQ 1024
#define DK 64
#define NP 4
#define SC2 0.1803368801111f   // 0.125 * log2(e)

typedef __attribute__((ext_vector_type(8))) short short8;
typedef __attribute__((ext_vector_type(4))) float f32x4;

__device__ __forceinline__ unsigned short f2bf(float f) {
    union { float f; unsigned u; } v; v.f = f;
    unsigned u = v.u;
    u += 0x7FFFu + ((u >> 16) & 1u);   // RNE
    return (unsigned short)(u >> 16);
}

// triangular tile map over (qt8 in 0..7 descending, kt in 0..2*qt8+1): 72 tiles
__device__ __forceinline__ void unpack_tile128(int G, int& qt8, int& kt) {
    int cum = 0;
    for (int q8 = 7; q8 >= 0; q8--) {
        int c = 2 * q8 + 2;
        if (G < cum + c) { qt8 = q8; kt = G - cum; return; }
        cum += c;
    }
    qt8 = 0; kt = 0;
}

// ---------------------------------------------------------------------------
// Prep 1: Wb[tg][co][ci] = bf16(W[co][ci][t]),  tg = toff[plane]+t (16 slices)
// ---------------------------------------------------------------------------
__global__ __launch_bounds__(256)
void prep_w_kernel(const float* __restrict__ w0, const float* __restrict__ w1,
                   const float* __restrict__ w2, const float* __restrict__ w3,
                   unsigned short* __restrict__ Wb) {
    int tg = blockIdx.y;
    int plane, t;
    if (tg < 1)      { plane = 0; t = tg; }
    else if (tg < 4) { plane = 1; t = tg - 1; }
    else if (tg < 9) { plane = 2; t = tg - 4; }
    else             { plane = 3; t = tg - 9; }
    const float* W = (plane == 0) ? w0 : (plane == 1) ? w1 : (plane == 2) ? w2 : w3;
    const int f = (plane == 0) ? 1 : (plane == 1) ? 3 : (plane == 2) ? 5 : 7;

    int co = blockIdx.x * 32 + (threadIdx.x >> 3);
    int c8 = threadIdx.x & 7;
    for (int it = 0; it < 8; it++) {
        int ci = c8 * 8 + it * 64;
        unsigned short o[8];
#pragma unroll
        for (int jj = 0; jj < 8; jj++)
            o[jj] = f2bf(W[(size_t)(co * C_CH + ci + jj) * f + t]);
        *(short8*)&Wb[((size_t)tg * C_CH + co) * C_CH + ci] = *(short8*)o;
    }
}

// ---------------------------------------------------------------------------
// Prep 2: Xt[tb][pos+4][ci] = bf16(X[tb][ci][pos]); rows 0..3 / 1028..1031 zero.
// ---------------------------------------------------------------------------
__global__ __launch_bounds__(256)
void prep_x_kernel(const float* __restrict__ Qin, const float* __restrict__ Kin,
                   unsigned short* __restrict__ Xt) {
    int tb = blockIdx.z;
    int tensor = tb >> 1, b = tb & 1;
    const float* X = (tensor ? Kin : Qin) + (size_t)b * C_CH * L_SEQ;
    unsigned short* O = Xt + (size_t)tb * 1032 * C_CH;

    int pos0 = blockIdx.x * 64;
    int ci0  = blockIdx.y * 64;
    int tid = threadIdx.x;

    __shared__ float tile[64][65];
    int tx = tid & 15, ty = tid >> 4;
#pragma unroll
    for (int rr = 0; rr < 4; rr++) {
        int ci_l = ty + rr * 16;
        float4 v = *(const float4*)&X[(size_t)(ci0 + ci_l) * L_SEQ + pos0 + tx * 4];
        tile[tx * 4 + 0][ci_l] = v.x;
        tile[tx * 4 + 1][ci_l] = v.y;
        tile[tx * 4 + 2][ci_l] = v.z;
        tile[tx * 4 + 3][ci_l] = v.w;
    }
    __syncthreads();
#pragma unroll
    for (int pp = 0; pp < 2; pp++) {
        int pos_l = (tid >> 3) + pp * 32;
        int cg = (tid & 7) * 8;
        unsigned short o[8];
#pragma unroll
        for (int jj = 0; jj < 8; jj++) o[jj] = f2bf(tile[pos_l][cg + jj]);
        *(short8*)&O[(size_t)(pos0 + pos_l + 4) * C_CH + ci0 + cg] = *(short8*)o;
    }
    if (blockIdx.x == 0) {
        int r = tid >> 6, cc = tid & 63;
        O[(size_t)r * C_CH + ci0 + cc] = 0;
    }
    if (blockIdx.x == 15) {
        int r = tid >> 6, cc = tid & 63;
        O[(size_t)(1028 + r) * C_CH + ci0 + cc] = 0;
    }
}

// ---------------------------------------------------------------------------
// Conv bf16-MFMA GEMM (unchanged). 512 blocks, 2/CU, f-complement map.
// ---------------------------------------------------------------------------
__global__ __launch_bounds__(256)
void conv_mfma_kernel(const unsigned short* __restrict__ Xt,
                      const unsigned short* __restrict__ Wb,
                      const float* __restrict__ b0, const float* __restrict__ b1,
                      const float* __restrict__ b2, const float* __restrict__ b3,
                      unsigned short* __restrict__ Qp, unsigned short* __restrict__ Kp) {
    const int fs[4]   = {1, 3, 5, 7};
    const int toff[4] = {0, 1, 4, 9};
    int id = blockIdx.x;
    int plane, rel;
    if (id < 128)      { plane = 0; rel = id; }
    else if (id < 256) { plane = 1; rel = id - 128; }
    else if (id < 384) { plane = 3; rel = id - 256; }
    else               { plane = 2; rel = id - 384; }
    int co0  = (rel & 3) * 128;
    int pos0 = ((rel >> 2) & 7) * 128;
    int tb   = rel >> 5;
    int tensor = tb >> 1, b = tb & 1;
    const int f   = fs[plane];
    const int pad = (f - 1) >> 1;
    const int n   = f * 16;
    const float* bias = (plane == 0) ? b0 : (plane == 1) ? b1 : (plane == 2) ? b2 : b3;
    unsigned short* Out = tensor ? Kp : Qp;
    const unsigned short* Xbase = Xt + (size_t)tb * 1032 * C_CH;

    __shared__ __align__(16) unsigned short As[2][4096];
    __shared__ __align__(16) unsigned short Bs[2][4096];

    int tid  = threadIdx.x;
    int w    = tid >> 6;
    int lane = tid & 63;
    int l15  = lane & 15;
    int quad = lane >> 4;
    int wm = (w & 1) * 64;
    int wn = (w >> 1) * 64;
    int rowL = tid >> 2;
    int cS   = tid & 3;

    int woff[2];
#pragma unroll
    for (int rep = 0; rep < 2; rep++) {
        int r = rowL + rep * 64;
        int line = r >> 1;
        int sl = (((r & 1) << 2) | cS) ^ (line & 7);
        woff[rep] = line * 64 + sl * 8;
    }
    int aoff[4], boff[4];
#pragma unroll
    for (int mi = 0; mi < 4; mi++) {
        int r = wm + mi * 16 + l15;
        int line = r >> 1;
        aoff[mi] = line * 64 + ((((r & 1) << 2) | quad) ^ (line & 7)) * 8;
        int r2 = wn + mi * 16 + l15;
        int line2 = r2 >> 1;
        boff[mi] = line2 * 64 + ((((r2 & 1) << 2) | quad) ^ (line2 & 7)) * 8;
    }

    f32x4 acc[4][4];
#pragma unroll
    for (int mi = 0; mi < 4; mi++)
#pragma unroll
        for (int ni = 0; ni < 4; ni++) acc[mi][ni] = (f32x4){0.f, 0.f, 0.f, 0.f};

    short8 pA[2], pB[2];
    {
        const unsigned short* Wsl = Wb + ((size_t)toff[plane] * C_CH + co0) * C_CH;
        const unsigned short* Xsl = Xbase + (size_t)(pos0 - pad + 4) * C_CH;
#pragma unroll
        for (int rep = 0; rep < 2; rep++) {
            int r = rowL + rep * 64;
            pA[rep] = *(const short8*)&Wsl[(size_t)r * C_CH + cS * 8];
            pB[rep] = *(const short8*)&Xsl[(size_t)r * C_CH + cS * 8];
        }
    }

    for (int it = 0; it < n; it++) {
        int cur = it & 1;
        *(short8*)&As[cur][woff[0]] = pA[0];
        *(short8*)&As[cur][woff[1]] = pA[1];
        *(short8*)&Bs[cur][woff[0]] = pB[0];
        *(short8*)&Bs[cur][woff[1]] = pB[1];
        __syncthreads();

        if (it + 1 < n) {
            int t = (it + 1) >> 4, cc = (it + 1) & 15;
            const unsigned short* Wsl =
                Wb + ((size_t)(toff[plane] + t) * C_CH + co0) * C_CH + cc * 32;
            const unsigned short* Xsl =
                Xbase + (size_t)(pos0 + t - pad + 4) * C_CH + cc * 32;
#pragma unroll
            for (int rep = 0; rep < 2; rep++) {
                int r = rowL + rep * 64;
                pA[rep] = *(const short8*)&Wsl[(size_t)r * C_CH + cS * 8];
                pB[rep] = *(const short8*)&Xsl[(size_t)r * C_CH + cS * 8];
            }
        }

        short8 af[4], bf[4];
#pragma unroll
        for (int mi = 0; mi < 4; mi++) af[mi] = *(const short8*)&As[cur][aoff[mi]];
#pragma unroll
        for (int ni = 0; ni < 4; ni++) bf[ni] = *(const short8*)&Bs[cur][boff[ni]];
#pragma unroll
        for (int mi = 0; mi < 4; mi++)
#pragma unroll
            for (int ni = 0; ni < 4; ni++)
                acc[mi][ni] = __builtin_amdgcn_mfma_f32_16x16x32_bf16(
                    af[mi], bf[ni], acc[mi][ni], 0, 0, 0);
    }

#pragma unroll
    for (int mi = 0; mi < 4; mi++)
#pragma unroll
        for (int r = 0; r < 4; r++) {
            int co = co0 + wm + mi * 16 + quad * 4 + r;
            int h = co >> 6, cl = co & 63;
            float bv = bias[co];
            size_t sbase = (size_t)((b * 8 + h) * NP + plane) * L_SEQ * DK;
#pragma unroll
            for (int ni = 0; ni < 4; ni++) {
                int pos = pos0 + wn + ni * 16 + l15;
                int l = cl * 16 + (pos >> 6);
                int d = pos & 63;
                Out[sbase + (size_t)l * DK + d] = f2bf(acc[mi][ni][r] + bv);
            }
        }
}

// ---------------------------------------------------------------------------
// Stats: 128q x 64k tile per block, 8 waves. pl[((bh*16+qt64)*16+kt)*256 + p*64+row].
// grid (72, 16 bh), 512 thr. No atomics, no barriers.
// ---------------------------------------------------------------------------
__global__ __launch_bounds__(512)
void attn_stats_kernel(const unsigned short* __restrict__ Qb,
                       const unsigned short* __restrict__ Kb,
                       float* __restrict__ pl) {
    int qt8, kt;
    unpack_tile128(blockIdx.x, qt8, kt);
    int bh = blockIdx.y;
    int tid = threadIdx.x;
    int w = tid >> 6, lane = tid & 63, l15 = lane & 15, quad = lane >> 4;
    int q0 = qt8 * 128, k0 = kt * 64;
    int qrow0 = q0 + w * 16;

    if (qrow0 + 15 < k0) return;   // fully masked wave (slot unused by combine)

    int b2 = bh >> 3, h2 = bh & 7;
    int plane  = b2 * 2 + (h2 >> 2);
    int b_orig = (h2 >> 1) & 1;
    int h_base = (h2 & 1) * 4;

    float l[NP][4];
#pragma unroll
    for (int p = 0; p < NP; p++)
        for (int r = 0; r < 4; r++) l[p][r] = 0.f;

#pragma unroll
    for (int p = 0; p < NP; p++) {
        size_t slice = (size_t)((b_orig * 8 + h_base + p) * NP + plane);
        const unsigned short* kb = Kb + slice * L_SEQ * DK;
        const unsigned short* qrow =
            Qb + (slice * L_SEQ + (size_t)(qrow0 + l15)) * DK + quad * 8;
        short8 qa0 = *(const short8*)(qrow);
        short8 qa1 = *(const short8*)(qrow + 32);

        f32x4 c[4];
#pragma unroll
        for (int s = 0; s < 4; s++) {
            const unsigned short* kr = kb + (size_t)(k0 + s * 16 + l15) * DK + quad * 8;
            short8 kb0 = *(const short8*)(kr);
            short8 kb1 = *(const short8*)(kr + 32);
            f32x4 acc = {0.f, 0.f, 0.f, 0.f};
            acc = __builtin_amdgcn_mfma_f32_16x16x32_bf16(qa0, kb0, acc, 0, 0, 0);
            acc = __builtin_amdgcn_mfma_f32_16x16x32_bf16(qa1, kb1, acc, 0, 0, 0);
            c[s] = acc;
        }
#pragma unroll
        for (int r = 0; r < 4; r++) {
            int qg = qrow0 + quad * 4 + r;
#pragma unroll
            for (int s = 0; s < 4; s++) {
                float x = c[s][r] * SC2;
                if (k0 + s * 16 + l15 > qg) x = -1e30f;
                l[p][r] += exp2f(x);
            }
        }
    }

    int qt64 = qt8 * 2 + (w >> 2);
    size_t base = ((size_t)(bh * 16 + qt64) * 16 + kt) * 256;
#pragma unroll
    for (int p = 0; p < NP; p++)
#pragma unroll
        for (int r = 0; r < 4; r++) {
            float ll = l[p][r];
            ll += __shfl_xor(ll, 1);
            ll += __shfl_xor(ll, 2);
            ll += __shfl_xor(ll, 4);
            ll += __shfl_xor(ll, 8);
            if (l15 == 0)
                pl[base + p * 64 + ((w & 3) * 16 + quad * 4 + r)] = ll;
        }
}

// ---------------------------------------------------------------------------
// Combine: z = log2(sum_{kt<=qt} pl); zero attn cols beyond diagonal.
// grid (16 qt64, 16 bh), 256 thr.
// ---------------------------------------------------------------------------
__global__ __launch_bounds__(256)
void attn_combine_kernel(const float* __restrict__ pl,
                         float* __restrict__ fstats,
                         float* __restrict__ out_attn) {
    int qt = blockIdx.x, bh = blockIdx.y;
    int tid = threadIdx.x;
    size_t sb = (size_t)(bh * 16 + qt) * 16 * 256;

    float l = 0.f;
    for (int kt = 0; kt <= qt; kt++)
        l += pl[sb + (size_t)kt * 256 + tid];
    fstats[(size_t)(bh * 16 + qt) * 256 + tid] = __log2f(l);

    int r = tid >> 2;
    float4 z = make_float4(0.f, 0.f, 0.f, 0.f);
    int kz = (qt + 1) * 64;
    size_t abase = ((size_t)bh * L_SEQ + qt * 64 + r) * L_SEQ;
    for (int k = kz + (tid & 3) * 4; k < L_SEQ; k += 16)
        *(float4*)&out_attn[abase + k] = z;
}

// ---------------------------------------------------------------------------
// Apply: 128q x 64k tile per block, 8 waves, attn write ONLY.
// attn = exp2(max_p(s2_p - z_p)). grid (72, 16 bh), 512 thr.
// ---------------------------------------------------------------------------
__global__ __launch_bounds__(512)
void attn_apply_kernel(const unsigned short* __restrict__ Qb,
                       const unsigned short* __restrict__ Kb,
                       const float* __restrict__ fstats,
                       float* __restrict__ out_attn) {
    int qt8, kt;
    unpack_tile128(blockIdx.x, qt8, kt);
    int bh = blockIdx.y;
    int tid = threadIdx.x;
    int w = tid >> 6, lane = tid & 63, l15 = lane & 15, quad = lane >> 4;
    int q0 = qt8 * 128, k0 = kt * 64;
    int qrow0 = q0 + w * 16;

    __shared__ float zsm[512];   // [p][row128]
    {
        int p = tid >> 7, row = tid & 127;
        int qt64 = qt8 * 2 + (row >> 6);
        zsm[tid] = fstats[(size_t)(bh * 16 + qt64) * 256 + p * 64 + (row & 63)];
    }
    __syncthreads();

    if (qrow0 + 15 < k0) {   // fully masked wave: zeros
#pragma unroll
        for (int s = 0; s < 4; s++)
#pragma unroll
            for (int r = 0; r < 4; r++) {
                int qg = qrow0 + quad * 4 + r;
                out_attn[((size_t)bh * L_SEQ + qg) * L_SEQ + k0 + s * 16 + l15] = 0.f;
            }
        return;
    }

    int b2 = bh >> 3, h2 = bh & 7;
    int plane  = b2 * 2 + (h2 >> 2);
    int b_orig = (h2 >> 1) & 1;
    int h_base = (h2 & 1) * 4;

    float run[4][4];
#pragma unroll
    for (int s = 0; s < 4; s++)
        for (int r = 0; r < 4; r++) run[s][r] = -1e30f;

#pragma unroll
    for (int p = 0; p < NP; p++) {
        size_t slice = (size_t)((b_orig * 8 + h_base + p) * NP + plane);
        const unsigned short* kb = Kb + slice * L_SEQ * DK;
        const unsigned short* qrow =
            Qb + (slice * L_SEQ + (size_t)(qrow0 + l15)) * DK + quad * 8;
        short8 qa0 = *(const short8*)(qrow);
        short8 qa1 = *(const short8*)(qrow + 32);

        f32x4 c[4];
#pragma unroll
        for (int s = 0; s < 4; s++) {
            const unsigned short* kr = kb + (size_t)(k0 + s * 16 + l15) * DK + quad * 8;
            short8 kb0 = *(const short8*)(kr);
            short8 kb1 = *(const short8*)(kr + 32);
            f32x4 acc = {0.f, 0.f, 0.f, 0.f};
            acc = __builtin_amdgcn_mfma_f32_16x16x32_bf16(qa0, kb0, acc, 0, 0, 0);
            acc = __builtin_amdgcn_mfma_f32_16x16x32_bf16(qa1, kb1, acc, 0, 0, 0);
            c[s] = acc;
        }
#pragma unroll
        for (int r = 0; r < 4; r++) {
            float zp = zsm[p * 128 + (w * 16 + quad * 4 + r)];
#pragma unroll
            for (int s = 0; s < 4; s++)
                run[s][r] = fmaxf(run[s][r], c[s][r] * SC2 - zp);
        }
    }

#pragma unroll
    for (int s = 0; s < 4; s++)
#pragma unroll
        for (int r = 0; r < 4; r++) {
            int qg = qrow0 + quad * 4 + r;
            int kg = k0 + s * 16 + l15;
            float a = (kg > qg) ? 0.f : exp2f(run[s][r]);
            out_attn[((size_t)bh * L_SEQ + qg) * L_SEQ + kg] = a;
        }
}

// ---------------------------------------------------------------------------
// ctx = attn @ V.  One block per (qt64, bh), 8 waves: wave w owns q-rows
// (w&3)*16 and d-pair (w>>2)*2 -> disjoint output, no reduction.
// V chunk (128k x 64d) staged bf16 in LDS. grid (16, 16), 512 thr.
// ---------------------------------------------------------------------------
__global__ __launch_bounds__(512)
void ctx_gemm_kernel(const float* __restrict__ attn, const float* __restrict__ V,
                     float* __restrict__ out_ctx) {
    int qt = 15 - blockIdx.x;   // big tiles first
    int bh = blockIdx.y;
    int tid = threadIdx.x;
    int w = tid >> 6, lane = tid & 63, l15 = lane & 15, quad = lane >> 4;
    int q0 = qt * 64;
    int nk = (qt + 1) * 64;
    int wq = (w & 3) * 16;
    int ds0 = (w >> 2) * 2;

    __shared__ __align__(16) unsigned short vts[64 * 136];   // [d][k] stride 136

    const float* Arow = attn + ((size_t)bh * L_SEQ + q0 + wq + l15) * L_SEQ;
    const float* Vb = V + (size_t)bh * L_SEQ * DK;

    f32x4 acc[2];
    acc[0] = (f32x4){0.f, 0.f, 0.f, 0.f};
    acc[1] = (f32x4){0.f, 0.f, 0.f, 0.f};

    for (int c0 = 0; c0 < nk; c0 += 128) {
        int rem = min(128, nk - c0);
        __syncthreads();
        {
            int kl = tid >> 2, db = (tid & 3) * 16;
            if (kl < rem) {
                const float* vr = Vb + (size_t)(c0 + kl) * DK + db;
                float vv[16];
                *(float4*)&vv[0]  = *(const float4*)(vr);
                *(float4*)&vv[4]  = *(const float4*)(vr + 4);
                *(float4*)&vv[8]  = *(const float4*)(vr + 8);
                *(float4*)&vv[12] = *(const float4*)(vr + 12);
#pragma unroll
                for (int jj = 0; jj < 16; jj++)
                    vts[(db + jj) * 136 + kl] = f2bf(vv[jj]);
            }
        }
        __syncthreads();

        int nss = rem >> 5;
        for (int ss = 0; ss < nss; ss++) {
            int kk = c0 + ss * 32 + quad * 8;
            float4 a0 = *(const float4*)&Arow[kk];
            float4 a1 = *(const float4*)&Arow[kk + 4];
            unsigned short af[8];
            af[0] = f2bf(a0.x); af[1] = f2bf(a0.y); af[2] = f2bf(a0.z); af[3] = f2bf(a0.w);
            af[4] = f2bf(a1.x); af[5] = f2bf(a1.y); af[6] = f2bf(a1.z); af[7] = f2bf(a1.w);
            short8 afv = *(short8*)af;
#pragma unroll
            for (int t = 0; t < 2; t++) {
                short8 bf = *(const short8*)&vts[((ds0 + t) * 16 + l15) * 136 +
                                                 ss * 32 + quad * 8];
                acc[t] = __builtin_amdgcn_mfma_f32_16x16x32_bf16(afv, bf, acc[t], 0, 0, 0);
            }
        }
    }

#pragma unroll
    for (int t = 0; t < 2; t++)
#pragma unroll
        for (int r = 0; r < 4; r++) {
            int qg = q0 + wq + quad * 4 + r;
            out_ctx[((size_t)bh * L_SEQ + qg) * DK + (ds0 + t) * 16 + l15] = acc[t][r];
        }
}

// ---------------------------------------------------------------------------
extern "C" void kernel_launch(void* const* d_in, const int* in_sizes, int n_in,
                              void* d_out, int out_size, void* d_ws, size_t ws_size,
                              hipStream_t stream) {
    const float* Q  = (const float*)d_in[0];
    const float* K  = (const float*)d_in[1];
    const float* V  = (const float*)d_in[2];
    const float* w0 = (const float*)d_in[4];
    const float* b0 = (const float*)d_in[5];
    const float* w1 = (const float*)d_in[6];
    const float* b1 = (const float*)d_in[7];
    const float* w2 = (const float*)d_in[8];
    const float* b2 = (const float*)d_in[9];
    const float* w3 = (const float*)d_in[10];
    const float* b3 = (const float*)d_in[11];

    char* ws = (char*)d_ws;
    unsigned short* Wb = (unsigned short*)(ws);                  // 8,388,608 B
    unsigned short* Xt = (unsigned short*)(ws + 8388608);        // 4,227,072 B
    unsigned short* Qp = (unsigned short*)(ws + 12615680);       // 8,388,608 B
    unsigned short* Kp = (unsigned short*)(ws + 21004288);       // 8,388,608 B
    // stats alias the Wb region (dead after conv):
    float* pl     = (float*)(ws);                                // 4,194,304 B
    float* fstats = (float*)(ws + 4194304);                      //   262,144 B

    float* out_ctx  = (float*)d_out;
    float* out_attn = out_ctx + 1048576;

    prep_w_kernel<<<dim3(16, 16), 256, 0, stream>>>(w0, w1, w2, w3, Wb);
    prep_x_kernel<<<dim3(16, 8, 4), 256, 0, stream>>>(Q, K, Xt);
    conv_mfma_kernel<<<dim3(512), 256, 0, stream>>>(Xt, Wb, b0, b1, b2, b3, Qp, Kp);
    attn_stats_kernel<<<dim3(72, 16), 512, 0, stream>>>(Qp, Kp, pl);
    attn_combine_kernel<<<dim3(16, 16), 256, 0, stream>>>(pl, fstats, out_attn);
    attn_apply_kernel<<<dim3(72, 16), 512, 0, stream>>>(Qp, Kp, fstats, out_attn);
    ctx_gemm_kernel<<<dim3(16, 16), 512, 0, stream>>>(out_attn, V, out_ctx);
}

// Round 10
// 359.177 us; speedup vs baseline: 1.0414x; 1.0414x over previous
//
#include <hip/hip_runtime.h>
#include <math.h>

#define C_CH 512
#define L_SEQ 1024
#define DK 64
#define NP 4
#define SC2 0.1803368801111f   // 0.125 * log2(e)

typedef __attribute__((ext_vector_type(8))) short short8;
typedef __attribute__((ext_vector_type(4))) float f32x4;

__device__ __forceinline__ unsigned short f2bf(float f) {
    union { float f; unsigned u; } v; v.f = f;
    unsigned u = v.u;
    u += 0x7FFFu + ((u >> 16) & 1u);   // RNE
    return (unsigned short)(u >> 16);
}

// triangular tile map over (qt8 in 0..7 descending, kt in 0..2*qt8+1): 72 tiles
__device__ __forceinline__ void unpack_tile128(int G, int& qt8, int& kt) {
    int cum = 0;
    for (int q8 = 7; q8 >= 0; q8--) {
        int c = 2 * q8 + 2;
        if (G < cum + c) { qt8 = q8; kt = G - cum; return; }
        cum += c;
    }
    qt8 = 0; kt = 0;
}

// Balanced kt-group mapping: 40 groups per bh, qt descending.
// ng(qt) = ceil((qt+1)/4); group j covers kt [j*n/ng, (j+1)*n/ng).
__device__ __forceinline__ void unpack_group(int G, int& qt, int& kt0, int& kt1,
                                             int& j, int& ng) {
    int q = 15, cum = 0, jj = 0;
    for (; q >= 0; q--) {
        int g = (q + 4) >> 2;
        if (G < cum + g) { jj = G - cum; break; }
        cum += g;
    }
    qt = q;
    ng = (q + 4) >> 2;
    j = jj;
    int n = q + 1;
    kt0 = (jj * n) / ng;
    kt1 = ((jj + 1) * n) / ng;
}

// ---------------------------------------------------------------------------
// Prep 1: Wb[tg][co][ci] = bf16(W[co][ci][t]),  tg = toff[plane]+t (16 slices)
// ---------------------------------------------------------------------------
__global__ __launch_bounds__(256)
void prep_w_kernel(const float* __restrict__ w0, const float* __restrict__ w1,
                   const float* __restrict__ w2, const float* __restrict__ w3,
                   unsigned short* __restrict__ Wb) {
    int tg = blockIdx.y;
    int plane, t;
    if (tg < 1)      { plane = 0; t = tg; }
    else if (tg < 4) { plane = 1; t = tg - 1; }
    else if (tg < 9) { plane = 2; t = tg - 4; }
    else             { plane = 3; t = tg - 9; }
    const float* W = (plane == 0) ? w0 : (plane == 1) ? w1 : (plane == 2) ? w2 : w3;
    const int f = (plane == 0) ? 1 : (plane == 1) ? 3 : (plane == 2) ? 5 : 7;

    int co = blockIdx.x * 32 + (threadIdx.x >> 3);
    int c8 = threadIdx.x & 7;
    for (int it = 0; it < 8; it++) {
        int ci = c8 * 8 + it * 64;
        unsigned short o[8];
#pragma unroll
        for (int jj = 0; jj < 8; jj++)
            o[jj] = f2bf(W[(size_t)(co * C_CH + ci + jj) * f + t]);
        *(short8*)&Wb[((size_t)tg * C_CH + co) * C_CH + ci] = *(short8*)o;
    }
}

// ---------------------------------------------------------------------------
// Prep 2: Xt[tb][pos+4][ci] = bf16(X[tb][ci][pos]); rows 0..3 / 1028..1031 zero.
// ---------------------------------------------------------------------------
__global__ __launch_bounds__(256)
void prep_x_kernel(const float* __restrict__ Qin, const float* __restrict__ Kin,
                   unsigned short* __restrict__ Xt) {
    int tb = blockIdx.z;
    int tensor = tb >> 1, b = tb & 1;
    const float* X = (tensor ? Kin : Qin) + (size_t)b * C_CH * L_SEQ;
    unsigned short* O = Xt + (size_t)tb * 1032 * C_CH;

    int pos0 = blockIdx.x * 64;
    int ci0  = blockIdx.y * 64;
    int tid = threadIdx.x;

    __shared__ float tile[64][65];
    int tx = tid & 15, ty = tid >> 4;
#pragma unroll
    for (int rr = 0; rr < 4; rr++) {
        int ci_l = ty + rr * 16;
        float4 v = *(const float4*)&X[(size_t)(ci0 + ci_l) * L_SEQ + pos0 + tx * 4];
        tile[tx * 4 + 0][ci_l] = v.x;
        tile[tx * 4 + 1][ci_l] = v.y;
        tile[tx * 4 + 2][ci_l] = v.z;
        tile[tx * 4 + 3][ci_l] = v.w;
    }
    __syncthreads();
#pragma unroll
    for (int pp = 0; pp < 2; pp++) {
        int pos_l = (tid >> 3) + pp * 32;
        int cg = (tid & 7) * 8;
        unsigned short o[8];
#pragma unroll
        for (int jj = 0; jj < 8; jj++) o[jj] = f2bf(tile[pos_l][cg + jj]);
        *(short8*)&O[(size_t)(pos0 + pos_l + 4) * C_CH + ci0 + cg] = *(short8*)o;
    }
    if (blockIdx.x == 0) {
        int r = tid >> 6, cc = tid & 63;
        O[(size_t)r * C_CH + ci0 + cc] = 0;
    }
    if (blockIdx.x == 15) {
        int r = tid >> 6, cc = tid & 63;
        O[(size_t)(1028 + r) * C_CH + ci0 + cc] = 0;
    }
}

// ---------------------------------------------------------------------------
// Conv bf16-MFMA GEMM. 1024 blocks (4/CU), 128co x 64pos tile each.
// id map: 0-255 f1, 256-511 f3, 512-767 f7, 768-1023 f5 -> each CU holds one
// block of each f (round-robin) = uniform 256 K-iters/CU.
// XOR-swizzled ping-pong LDS; LDS-staged vectorized epilogue.
// ---------------------------------------------------------------------------
__global__ __launch_bounds__(256)
void conv_mfma_kernel(const unsigned short* __restrict__ Xt,
                      const unsigned short* __restrict__ Wb,
                      const float* __restrict__ b0, const float* __restrict__ b1,
                      const float* __restrict__ b2, const float* __restrict__ b3,
                      unsigned short* __restrict__ Qp, unsigned short* __restrict__ Kp) {
    const int fs[4]   = {1, 3, 5, 7};
    const int toff[4] = {0, 1, 4, 9};
    int id = blockIdx.x;
    int plane = (id < 256) ? 0 : (id < 512) ? 1 : (id < 768) ? 3 : 2;
    int rel = id & 255;
    int co0  = (rel & 3) * 128;
    int pos0 = ((rel >> 2) & 15) * 64;
    int tb   = rel >> 6;
    int tensor = tb >> 1, b = tb & 1;
    const int f   = fs[plane];
    const int pad = (f - 1) >> 1;
    const int n   = f * 16;
    const float* bias = (plane == 0) ? b0 : (plane == 1) ? b1 : (plane == 2) ? b2 : b3;
    unsigned short* Out = tensor ? Kp : Qp;
    const unsigned short* Xbase = Xt + (size_t)tb * 1032 * C_CH;

    __shared__ __align__(16) unsigned short As[2][4096];   // 128 rows x 32 k
    __shared__ __align__(16) unsigned short Bs[2][2048];   //  64 rows x 32 k

    int tid  = threadIdx.x;
    int w    = tid >> 6;
    int lane = tid & 63;
    int l15  = lane & 15;
    int quad = lane >> 4;
    int wm = (w & 1) * 64;     // co half
    int wn = (w >> 1) * 32;    // pos half

    // staging: thread covers A slots (rA0, sA) & (rA0+64, sA), B slot (rA0, sA)
    int rA0 = tid >> 2, sA = tid & 3;
    int woffA[2], woffB;
#pragma unroll
    for (int rep = 0; rep < 2; rep++) {
        int r = rA0 + rep * 64;
        int line = r >> 1;
        woffA[rep] = line * 64 + (((((r & 1) << 2) | sA)) ^ (line & 7)) * 8;
    }
    {
        int line = rA0 >> 1;
        woffB = line * 64 + (((((rA0 & 1) << 2) | sA)) ^ (line & 7)) * 8;
    }
    int aoff[4], boff[2];
#pragma unroll
    for (int mi = 0; mi < 4; mi++) {
        int r = wm + mi * 16 + l15;
        int line = r >> 1;
        aoff[mi] = line * 64 + ((((r & 1) << 2) | quad) ^ (line & 7)) * 8;
    }
#pragma unroll
    for (int ni = 0; ni < 2; ni++) {
        int r = wn + ni * 16 + l15;
        int line = r >> 1;
        boff[ni] = line * 64 + ((((r & 1) << 2) | quad) ^ (line & 7)) * 8;
    }

    f32x4 acc[4][2];
#pragma unroll
    for (int mi = 0; mi < 4; mi++)
#pragma unroll
        for (int ni = 0; ni < 2; ni++) acc[mi][ni] = (f32x4){0.f, 0.f, 0.f, 0.f};

    short8 pA[2], pB;
    {
        const unsigned short* Wsl = Wb + ((size_t)toff[plane] * C_CH + co0) * C_CH;
        const unsigned short* Xsl = Xbase + (size_t)(pos0 - pad + 4) * C_CH;
        pA[0] = *(const short8*)&Wsl[(size_t)rA0 * C_CH + sA * 8];
        pA[1] = *(const short8*)&Wsl[(size_t)(rA0 + 64) * C_CH + sA * 8];
        pB    = *(const short8*)&Xsl[(size_t)rA0 * C_CH + sA * 8];
    }

    for (int it = 0; it < n; it++) {
        int cur = it & 1;
        *(short8*)&As[cur][woffA[0]] = pA[0];
        *(short8*)&As[cur][woffA[1]] = pA[1];
        *(short8*)&Bs[cur][woffB]    = pB;
        __syncthreads();

        if (it + 1 < n) {
            int t = (it + 1) >> 4, cc = (it + 1) & 15;
            const unsigned short* Wsl =
                Wb + ((size_t)(toff[plane] + t) * C_CH + co0) * C_CH + cc * 32;
            const unsigned short* Xsl =
                Xbase + (size_t)(pos0 + t - pad + 4) * C_CH + cc * 32;
            pA[0] = *(const short8*)&Wsl[(size_t)rA0 * C_CH + sA * 8];
            pA[1] = *(const short8*)&Wsl[(size_t)(rA0 + 64) * C_CH + sA * 8];
            pB    = *(const short8*)&Xsl[(size_t)rA0 * C_CH + sA * 8];
        }

        short8 af[4], bf[2];
#pragma unroll
        for (int mi = 0; mi < 4; mi++) af[mi] = *(const short8*)&As[cur][aoff[mi]];
#pragma unroll
        for (int ni = 0; ni < 2; ni++) bf[ni] = *(const short8*)&Bs[cur][boff[ni]];
#pragma unroll
        for (int mi = 0; mi < 4; mi++)
#pragma unroll
            for (int ni = 0; ni < 2; ni++)
                acc[mi][ni] = __builtin_amdgcn_mfma_f32_16x16x32_bf16(
                    af[mi], bf[ni], acc[mi][ni], 0, 0, 0);
    }

    // epilogue via LDS: Cs[co_l][pos_l] bf16, then coalesced b128 rows out.
    __syncthreads();
    unsigned short* Cs = &As[0][0];   // 8192 shorts = 128 x 64
#pragma unroll
    for (int mi = 0; mi < 4; mi++)
#pragma unroll
        for (int r = 0; r < 4; r++) {
            int co_l = wm + mi * 16 + quad * 4 + r;
            float bv = bias[co0 + co_l];
#pragma unroll
            for (int ni = 0; ni < 2; ni++)
                Cs[co_l * 64 + wn + ni * 16 + l15] = f2bf(acc[mi][ni][r] + bv);
        }
    __syncthreads();
    {
        int co_l = tid >> 1, half = tid & 1;
        int co = co0 + co_l;
        int h = co >> 6, cl = co & 63;
        int l = cl * 16 + (pos0 >> 6);
        size_t obase =
            ((size_t)((b * 8 + h) * NP + plane) * L_SEQ + l) * DK + half * 32;
#pragma unroll
        for (int k = 0; k < 4; k++)
            *(short8*)&Out[obase + k * 8] =
                *(const short8*)&Cs[co_l * 64 + half * 32 + k * 8];
    }
}

// ---------------------------------------------------------------------------
// Stats: 128q x 64k tile per block, 8 waves. pl[((bh*16+qt64)*16+kt)*256+p*64+row].
// grid (72, 16 bh), 512 thr. No atomics, no barriers.
// ---------------------------------------------------------------------------
__global__ __launch_bounds__(512)
void attn_stats_kernel(const unsigned short* __restrict__ Qb,
                       const unsigned short* __restrict__ Kb,
                       float* __restrict__ pl) {
    int qt8, kt;
    unpack_tile128(blockIdx.x, qt8, kt);
    int bh = blockIdx.y;
    int tid = threadIdx.x;
    int w = tid >> 6, lane = tid & 63, l15 = lane & 15, quad = lane >> 4;
    int q0 = qt8 * 128, k0 = kt * 64;
    int qrow0 = q0 + w * 16;

    if (qrow0 + 15 < k0) return;   // fully masked wave (slot unused later)

    int b2 = bh >> 3, h2 = bh & 7;
    int plane  = b2 * 2 + (h2 >> 2);
    int b_orig = (h2 >> 1) & 1;
    int h_base = (h2 & 1) * 4;

    float l[NP][4];
#pragma unroll
    for (int p = 0; p < NP; p++)
        for (int r = 0; r < 4; r++) l[p][r] = 0.f;

#pragma unroll
    for (int p = 0; p < NP; p++) {
        size_t slice = (size_t)((b_orig * 8 + h_base + p) * NP + plane);
        const unsigned short* kb = Kb + slice * L_SEQ * DK;
        const unsigned short* qrow =
            Qb + (slice * L_SEQ + (size_t)(qrow0 + l15)) * DK + quad * 8;
        short8 qa0 = *(const short8*)(qrow);
        short8 qa1 = *(const short8*)(qrow + 32);

        f32x4 c[4];
#pragma unroll
        for (int s = 0; s < 4; s++) {
            const unsigned short* kr = kb + (size_t)(k0 + s * 16 + l15) * DK + quad * 8;
            short8 kb0 = *(const short8*)(kr);
            short8 kb1 = *(const short8*)(kr + 32);
            f32x4 acc = {0.f, 0.f, 0.f, 0.f};
            acc = __builtin_amdgcn_mfma_f32_16x16x32_bf16(qa0, kb0, acc, 0, 0, 0);
            acc = __builtin_amdgcn_mfma_f32_16x16x32_bf16(qa1, kb1, acc, 0, 0, 0);
            c[s] = acc;
        }
#pragma unroll
        for (int r = 0; r < 4; r++) {
            int qg = qrow0 + quad * 4 + r;
#pragma unroll
            for (int s = 0; s < 4; s++) {
                float x = c[s][r] * SC2;
                if (k0 + s * 16 + l15 > qg) x = -1e30f;
                l[p][r] += exp2f(x);
            }
        }
    }

    int qt64 = qt8 * 2 + (w >> 2);
    size_t base = ((size_t)(bh * 16 + qt64) * 16 + kt) * 256;
#pragma unroll
    for (int p = 0; p < NP; p++)
#pragma unroll
        for (int r = 0; r < 4; r++) {
            float ll = l[p][r];
            ll += __shfl_xor(ll, 1);
            ll += __shfl_xor(ll, 2);
            ll += __shfl_xor(ll, 4);
            ll += __shfl_xor(ll, 8);
            if (l15 == 0)
                pl[base + p * 64 + ((w & 3) * 16 + quad * 4 + r)] = ll;
        }
}

// ---------------------------------------------------------------------------
// Apply (+ inlined combine): grid (128, 16): 72 real tiles + 56 zero tiles.
// z computed per-block from pl; attn = exp2(max_p(s2_p - z_p)).
// ---------------------------------------------------------------------------
__global__ __launch_bounds__(512)
void attn_apply_kernel(const unsigned short* __restrict__ Qb,
                       const unsigned short* __restrict__ Kb,
                       const float* __restrict__ pl,
                       float* __restrict__ out_attn) {
    int G = blockIdx.x;
    int bh = blockIdx.y;
    int tid = threadIdx.x;
    int w = tid >> 6, lane = tid & 63, l15 = lane & 15, quad = lane >> 4;

    int qt8, kt;
    if (G >= 72) {   // pure zero tile
        int z = G - 72, cum = 0;
        qt8 = 0; kt = 0;
        for (int q8 = 0; q8 < 8; q8++) {
            int c = 14 - 2 * q8;
            if (z < cum + c) { qt8 = q8; kt = 2 * q8 + 2 + (z - cum); break; }
            cum += c;
        }
        int q0 = qt8 * 128, k0 = kt * 64;
        int qrow0 = q0 + w * 16;
#pragma unroll
        for (int s = 0; s < 4; s++)
#pragma unroll
            for (int r = 0; r < 4; r++) {
                int qg = qrow0 + quad * 4 + r;
                out_attn[((size_t)bh * L_SEQ + qg) * L_SEQ + k0 + s * 16 + l15] = 0.f;
            }
        return;
    }

    unpack_tile128(G, qt8, kt);
    int q0 = qt8 * 128, k0 = kt * 64;
    int qrow0 = q0 + w * 16;

    // inlined combine: z = log2(sum_kt pl) for this block's 128 q-rows
    __shared__ float zsm[512];   // [p][row128]
    {
        int p = tid >> 7, row = tid & 127;
        int qt64 = qt8 * 2 + (row >> 6);
        size_t sb = (size_t)(bh * 16 + qt64) * 16 * 256 + p * 64 + (row & 63);
        float lsum = 0.f;
        for (int kt2 = 0; kt2 <= qt64; kt2++)
            lsum += pl[sb + (size_t)kt2 * 256];
        zsm[tid] = __log2f(lsum);
    }
    __syncthreads();

    if (qrow0 + 15 < k0) {   // fully masked wave: zeros
#pragma unroll
        for (int s = 0; s < 4; s++)
#pragma unroll
            for (int r = 0; r < 4; r++) {
                int qg = qrow0 + quad * 4 + r;
                out_attn[((size_t)bh * L_SEQ + qg) * L_SEQ + k0 + s * 16 + l15] = 0.f;
            }
        return;
    }

    int b2 = bh >> 3, h2 = bh & 7;
    int plane  = b2 * 2 + (h2 >> 2);
    int b_orig = (h2 >> 1) & 1;
    int h_base = (h2 & 1) * 4;

    float run[4][4];
#pragma unroll
    for (int s = 0; s < 4; s++)
        for (int r = 0; r < 4; r++) run[s][r] = -1e30f;

#pragma unroll
    for (int p = 0; p < NP; p++) {
        size_t slice = (size_t)((b_orig * 8 + h_base + p) * NP + plane);
        const unsigned short* kb = Kb + slice * L_SEQ * DK;
        const unsigned short* qrow =
            Qb + (slice * L_SEQ + (size_t)(qrow0 + l15)) * DK + quad * 8;
        short8 qa0 = *(const short8*)(qrow);
        short8 qa1 = *(const short8*)(qrow + 32);

        f32x4 c[4];
#pragma unroll
        for (int s = 0; s < 4; s++) {
            const unsigned short* kr = kb + (size_t)(k0 + s * 16 + l15) * DK + quad * 8;
            short8 kb0 = *(const short8*)(kr);
            short8 kb1 = *(const short8*)(kr + 32);
            f32x4 acc = {0.f, 0.f, 0.f, 0.f};
            acc = __builtin_amdgcn_mfma_f32_16x16x32_bf16(qa0, kb0, acc, 0, 0, 0);
            acc = __builtin_amdgcn_mfma_f32_16x16x32_bf16(qa1, kb1, acc, 0, 0, 0);
            c[s] = acc;
        }
#pragma unroll
        for (int r = 0; r < 4; r++) {
            float zp = zsm[p * 128 + (w * 16 + quad * 4 + r)];
#pragma unroll
            for (int s = 0; s < 4; s++)
                run[s][r] = fmaxf(run[s][r], c[s][r] * SC2 - zp);
        }
    }

#pragma unroll
    for (int s = 0; s < 4; s++)
#pragma unroll
        for (int r = 0; r < 4; r++) {
            int qg = qrow0 + quad * 4 + r;
            int kg = k0 + s * 16 + l15;
            float a = (kg > qg) ? 0.f : exp2f(run[s][r]);
            out_attn[((size_t)bh * L_SEQ + qg) * L_SEQ + kg] = a;
        }
}

// ---------------------------------------------------------------------------
// ctx partials: grouped balanced grid (40, 16), 256 thr; block covers <=4
// k-tiles of 64, wave w owns q-rows w*16..+15. pctx[((bh*16+qt)*4+j)*4096+...].
// ---------------------------------------------------------------------------
__global__ __launch_bounds__(256)
void ctx_gemm_kernel(const float* __restrict__ attn, const float* __restrict__ V,
                     float* __restrict__ pctx) {
    int qt, kt0, kt1, j, ng;
    unpack_group(blockIdx.x, qt, kt0, kt1, j, ng);
    int bh = blockIdx.y;
    int tid = threadIdx.x;
    int w = tid >> 6, lane = tid & 63, l15 = lane & 15, quad = lane >> 4;
    int q0 = qt * 64;

    __shared__ __align__(16) unsigned short vts[2][64 * 80];

    const float* Arow = attn + ((size_t)bh * L_SEQ + q0 + w * 16 + l15) * L_SEQ;
    const float* Vb = V + (size_t)bh * L_SEQ * DK;

    f32x4 acc[4];
#pragma unroll
    for (int ds = 0; ds < 4; ds++) acc[ds] = (f32x4){0.f, 0.f, 0.f, 0.f};

    for (int kt = kt0; kt < kt1; kt++) {
        int k0 = kt * 64;
        unsigned short* vb = vts[kt & 1];
        {
            int kl = tid >> 2, db = (tid & 3) * 16;
            const float* vr = Vb + (size_t)(k0 + kl) * DK + db;
            float vv[16];
            *(float4*)&vv[0]  = *(const float4*)(vr);
            *(float4*)&vv[4]  = *(const float4*)(vr + 4);
            *(float4*)&vv[8]  = *(const float4*)(vr + 8);
            *(float4*)&vv[12] = *(const float4*)(vr + 12);
#pragma unroll
            for (int jj = 0; jj < 16; jj++)
                vb[(db + jj) * 80 + kl] = f2bf(vv[jj]);
        }
        __syncthreads();

        // a-fragments straight from attn (f32 -> bf16)
        int kk = k0 + quad * 8;
        float4 a0 = *(const float4*)&Arow[kk];
        float4 a1 = *(const float4*)&Arow[kk + 4];
        float4 a2 = *(const float4*)&Arow[kk + 32];
        float4 a3 = *(const float4*)&Arow[kk + 36];
        unsigned short af[16];
        af[0] = f2bf(a0.x); af[1] = f2bf(a0.y); af[2] = f2bf(a0.z); af[3] = f2bf(a0.w);
        af[4] = f2bf(a1.x); af[5] = f2bf(a1.y); af[6] = f2bf(a1.z); af[7] = f2bf(a1.w);
        af[8]  = f2bf(a2.x); af[9]  = f2bf(a2.y); af[10] = f2bf(a2.z); af[11] = f2bf(a2.w);
        af[12] = f2bf(a3.x); af[13] = f2bf(a3.y); af[14] = f2bf(a3.z); af[15] = f2bf(a3.w);
        short8 af0 = *(short8*)&af[0];
        short8 af1 = *(short8*)&af[8];
#pragma unroll
        for (int ds = 0; ds < 4; ds++) {
            short8 bf0 = *(const short8*)&vb[(ds * 16 + l15) * 80 + quad * 8];
            short8 bf1 = *(const short8*)&vb[(ds * 16 + l15) * 80 + 32 + quad * 8];
            acc[ds] = __builtin_amdgcn_mfma_f32_16x16x32_bf16(af0, bf0, acc[ds], 0, 0, 0);
            acc[ds] = __builtin_amdgcn_mfma_f32_16x16x32_bf16(af1, bf1, acc[ds], 0, 0, 0);
        }
    }

    size_t pbase = ((size_t)(bh * 16 + qt) * 4 + j) * 4096;
#pragma unroll
    for (int ds = 0; ds < 4; ds++)
#pragma unroll
        for (int r = 0; r < 4; r++) {
            int qloc = w * 16 + quad * 4 + r;
            pctx[pbase + (size_t)qloc * 64 + ds * 16 + l15] = acc[ds][r];
        }
}

// ---------------------------------------------------------------------------
// Reduce ctx partials: out_ctx = sum over ng slots. grid (16 qt, 16 bh).
// ---------------------------------------------------------------------------
__global__ __launch_bounds__(256)
void ctx_reduce_kernel(const float* __restrict__ pctx, float* __restrict__ out_ctx) {
    int qt = blockIdx.x, bh = blockIdx.y;
    int tid = threadIdx.x;
    int ng = (qt + 4) >> 2;
    size_t base = (size_t)(bh * 16 + qt) * 4 * 4096;
    int row = tid >> 2, c = (tid & 3) * 16;
    size_t off = (size_t)row * 64 + c;

    float4 a0 = *(const float4*)&pctx[base + off];
    float4 a1 = *(const float4*)&pctx[base + off + 4];
    float4 a2 = *(const float4*)&pctx[base + off + 8];
    float4 a3 = *(const float4*)&pctx[base + off + 12];
    for (int g = 1; g < ng; g++) {
        size_t gb = base + (size_t)g * 4096 + off;
        float4 b0 = *(const float4*)&pctx[gb];
        float4 b1 = *(const float4*)&pctx[gb + 4];
        float4 b2 = *(const float4*)&pctx[gb + 8];
        float4 b3 = *(const float4*)&pctx[gb + 12];
        a0.x += b0.x; a0.y += b0.y; a0.z += b0.z; a0.w += b0.w;
        a1.x += b1.x; a1.y += b1.y; a1.z += b1.z; a1.w += b1.w;
        a2.x += b2.x; a2.y += b2.y; a2.z += b2.z; a2.w += b2.w;
        a3.x += b3.x; a3.y += b3.y; a3.z += b3.z; a3.w += b3.w;
    }
    size_t ob = ((size_t)bh * L_SEQ + qt * 64 + row) * DK + c;
    *(float4*)&out_ctx[ob]      = a0;
    *(float4*)&out_ctx[ob + 4]  = a1;
    *(float4*)&out_ctx[ob + 8]  = a2;
    *(float4*)&out_ctx[ob + 12] = a3;
}

// ---------------------------------------------------------------------------
extern "C" void kernel_launch(void* const* d_in, const int* in_sizes, int n_in,
                              void* d_out, int out_size, void* d_ws, size_t ws_size,
                              hipStream_t stream) {
    const float* Q  = (const float*)d_in[0];
    const float* K  = (const float*)d_in[1];
    const float* V  = (const float*)d_in[2];
    const float* w0 = (const float*)d_in[4];
    const float* b0 = (const float*)d_in[5];
    const float* w1 = (const float*)d_in[6];
    const float* b1 = (const float*)d_in[7];
    const float* w2 = (const float*)d_in[8];
    const float* b2 = (const float*)d_in[9];
    const float* w3 = (const float*)d_in[10];
    const float* b3 = (const float*)d_in[11];

    char* ws = (char*)d_ws;
    unsigned short* Wb = (unsigned short*)(ws);                  // 8,388,608 B
    unsigned short* Xt = (unsigned short*)(ws + 8388608);        // 4,227,072 B
    unsigned short* Qp = (unsigned short*)(ws + 12615680);       // 8,388,608 B
    unsigned short* Kp = (unsigned short*)(ws + 21004288);       // 8,388,608 B
    float* pctx        = (float*)(ws + 29392896);                // 16,777,216 B
    // pl aliases the Wb region (dead after conv): 16*16*16*256*4 = 4 MB
    float* pl = (float*)(ws);

    float* out_ctx  = (float*)d_out;
    float* out_attn = out_ctx + 1048576;

    prep_w_kernel<<<dim3(16, 16), 256, 0, stream>>>(w0, w1, w2, w3, Wb);
    prep_x_kernel<<<dim3(16, 8, 4), 256, 0, stream>>>(Q, K, Xt);
    conv_mfma_kernel<<<dim3(1024), 256, 0, stream>>>(Xt, Wb, b0, b1, b2, b3, Qp, Kp);
    attn_stats_kernel<<<dim3(72, 16), 512, 0, stream>>>(Qp, Kp, pl);
    attn_apply_kernel<<<dim3(128, 16), 512, 0, stream>>>(Qp, Kp, pl, out_attn);
    ctx_gemm_kernel<<<dim3(40, 16), 256, 0, stream>>>(out_attn, V, pctx);
    ctx_reduce_kernel<<<dim3(16, 16), 256, 0, stream>>>(pctx, out_ctx);
}

// Round 11
// 341.262 us; speedup vs baseline: 1.0961x; 1.0525x over previous
//
#include <hip/hip_runtime.h>
#include <math.h>

#define C_CH 512
#define L_SEQ 1024
#define DK 64
#define NP 4
#define SC2 0.1803368801111f   // 0.125 * log2(e)

typedef __attribute__((ext_vector_type(8))) short short8;
typedef __attribute__((ext_vector_type(4))) float f32x4;

__device__ __forceinline__ unsigned short f2bf(float f) {
    union { float f; unsigned u; } v; v.f = f;
    unsigned u = v.u;
    u += 0x7FFFu + ((u >> 16) & 1u);   // RNE
    return (unsigned short)(u >> 16);
}

// Balanced kt-group mapping: 40 groups per bh, qt descending.
// ng(qt) = ceil((qt+1)/4); group j covers kt [j*n/ng, (j+1)*n/ng).
__device__ __forceinline__ void unpack_group(int G, int& qt, int& kt0, int& kt1,
                                             int& j, int& ng) {
    int q = 15, cum = 0, jj = 0;
    for (; q >= 0; q--) {
        int g = (q + 4) >> 2;
        if (G < cum + g) { jj = G - cum; break; }
        cum += g;
    }
    qt = q;
    ng = (q + 4) >> 2;
    j = jj;
    int n = q + 1;
    kt0 = (jj * n) / ng;
    kt1 = ((jj + 1) * n) / ng;
}

// ---------------------------------------------------------------------------
// Prep 1: Wb[tg][co][ci] = bf16(W[co][ci][t]),  tg = toff[plane]+t (16 slices)
// ---------------------------------------------------------------------------
__global__ __launch_bounds__(256)
void prep_w_kernel(const float* __restrict__ w0, const float* __restrict__ w1,
                   const float* __restrict__ w2, const float* __restrict__ w3,
                   unsigned short* __restrict__ Wb) {
    int tg = blockIdx.y;
    int plane, t;
    if (tg < 1)      { plane = 0; t = tg; }
    else if (tg < 4) { plane = 1; t = tg - 1; }
    else if (tg < 9) { plane = 2; t = tg - 4; }
    else             { plane = 3; t = tg - 9; }
    const float* W = (plane == 0) ? w0 : (plane == 1) ? w1 : (plane == 2) ? w2 : w3;
    const int f = (plane == 0) ? 1 : (plane == 1) ? 3 : (plane == 2) ? 5 : 7;

    int co = blockIdx.x * 32 + (threadIdx.x >> 3);
    int c8 = threadIdx.x & 7;
    for (int it = 0; it < 8; it++) {
        int ci = c8 * 8 + it * 64;
        unsigned short o[8];
#pragma unroll
        for (int jj = 0; jj < 8; jj++)
            o[jj] = f2bf(W[(size_t)(co * C_CH + ci + jj) * f + t]);
        *(short8*)&Wb[((size_t)tg * C_CH + co) * C_CH + ci] = *(short8*)o;
    }
}

// ---------------------------------------------------------------------------
// Prep 2: Xt[tb][pos+4][ci] = bf16(X[tb][ci][pos]); rows 0..3 / 1028..1031 zero.
// ---------------------------------------------------------------------------
__global__ __launch_bounds__(256)
void prep_x_kernel(const float* __restrict__ Qin, const float* __restrict__ Kin,
                   unsigned short* __restrict__ Xt) {
    int tb = blockIdx.z;
    int tensor = tb >> 1, b = tb & 1;
    const float* X = (tensor ? Kin : Qin) + (size_t)b * C_CH * L_SEQ;
    unsigned short* O = Xt + (size_t)tb * 1032 * C_CH;

    int pos0 = blockIdx.x * 64;
    int ci0  = blockIdx.y * 64;
    int tid = threadIdx.x;

    __shared__ float tile[64][65];
    int tx = tid & 15, ty = tid >> 4;
#pragma unroll
    for (int rr = 0; rr < 4; rr++) {
        int ci_l = ty + rr * 16;
        float4 v = *(const float4*)&X[(size_t)(ci0 + ci_l) * L_SEQ + pos0 + tx * 4];
        tile[tx * 4 + 0][ci_l] = v.x;
        tile[tx * 4 + 1][ci_l] = v.y;
        tile[tx * 4 + 2][ci_l] = v.z;
        tile[tx * 4 + 3][ci_l] = v.w;
    }
    __syncthreads();
#pragma unroll
    for (int pp = 0; pp < 2; pp++) {
        int pos_l = (tid >> 3) + pp * 32;
        int cg = (tid & 7) * 8;
        unsigned short o[8];
#pragma unroll
        for (int jj = 0; jj < 8; jj++) o[jj] = f2bf(tile[pos_l][cg + jj]);
        *(short8*)&O[(size_t)(pos0 + pos_l + 4) * C_CH + ci0 + cg] = *(short8*)o;
    }
    if (blockIdx.x == 0) {
        int r = tid >> 6, cc = tid & 63;
        O[(size_t)r * C_CH + ci0 + cc] = 0;
    }
    if (blockIdx.x == 15) {
        int r = tid >> 6, cc = tid & 63;
        O[(size_t)(1028 + r) * C_CH + ci0 + cc] = 0;
    }
}

// ---------------------------------------------------------------------------
// Conv bf16-MFMA GEMM. 1024 blocks (4/CU), 128co x 64pos tile each. (R10)
// ---------------------------------------------------------------------------
__global__ __launch_bounds__(256)
void conv_mfma_kernel(const unsigned short* __restrict__ Xt,
                      const unsigned short* __restrict__ Wb,
                      const float* __restrict__ b0, const float* __restrict__ b1,
                      const float* __restrict__ b2, const float* __restrict__ b3,
                      unsigned short* __restrict__ Qp, unsigned short* __restrict__ Kp) {
    const int fs[4]   = {1, 3, 5, 7};
    const int toff[4] = {0, 1, 4, 9};
    int id = blockIdx.x;
    int plane = (id < 256) ? 0 : (id < 512) ? 1 : (id < 768) ? 3 : 2;
    int rel = id & 255;
    int co0  = (rel & 3) * 128;
    int pos0 = ((rel >> 2) & 15) * 64;
    int tb   = rel >> 6;
    int tensor = tb >> 1, b = tb & 1;
    const int f   = fs[plane];
    const int pad = (f - 1) >> 1;
    const int n   = f * 16;
    const float* bias = (plane == 0) ? b0 : (plane == 1) ? b1 : (plane == 2) ? b2 : b3;
    unsigned short* Out = tensor ? Kp : Qp;
    const unsigned short* Xbase = Xt + (size_t)tb * 1032 * C_CH;

    __shared__ __align__(16) unsigned short As[2][4096];   // 128 rows x 32 k
    __shared__ __align__(16) unsigned short Bs[2][2048];   //  64 rows x 32 k

    int tid  = threadIdx.x;
    int w    = tid >> 6;
    int lane = tid & 63;
    int l15  = lane & 15;
    int quad = lane >> 4;
    int wm = (w & 1) * 64;     // co half
    int wn = (w >> 1) * 32;    // pos half

    int rA0 = tid >> 2, sA = tid & 3;
    int woffA[2], woffB;
#pragma unroll
    for (int rep = 0; rep < 2; rep++) {
        int r = rA0 + rep * 64;
        int line = r >> 1;
        woffA[rep] = line * 64 + (((((r & 1) << 2) | sA)) ^ (line & 7)) * 8;
    }
    {
        int line = rA0 >> 1;
        woffB = line * 64 + (((((rA0 & 1) << 2) | sA)) ^ (line & 7)) * 8;
    }
    int aoff[4], boff[2];
#pragma unroll
    for (int mi = 0; mi < 4; mi++) {
        int r = wm + mi * 16 + l15;
        int line = r >> 1;
        aoff[mi] = line * 64 + ((((r & 1) << 2) | quad) ^ (line & 7)) * 8;
    }
#pragma unroll
    for (int ni = 0; ni < 2; ni++) {
        int r = wn + ni * 16 + l15;
        int line = r >> 1;
        boff[ni] = line * 64 + ((((r & 1) << 2) | quad) ^ (line & 7)) * 8;
    }

    f32x4 acc[4][2];
#pragma unroll
    for (int mi = 0; mi < 4; mi++)
#pragma unroll
        for (int ni = 0; ni < 2; ni++) acc[mi][ni] = (f32x4){0.f, 0.f, 0.f, 0.f};

    short8 pA[2], pB;
    {
        const unsigned short* Wsl = Wb + ((size_t)toff[plane] * C_CH + co0) * C_CH;
        const unsigned short* Xsl = Xbase + (size_t)(pos0 - pad + 4) * C_CH;
        pA[0] = *(const short8*)&Wsl[(size_t)rA0 * C_CH + sA * 8];
        pA[1] = *(const short8*)&Wsl[(size_t)(rA0 + 64) * C_CH + sA * 8];
        pB    = *(const short8*)&Xsl[(size_t)rA0 * C_CH + sA * 8];
    }

    for (int it = 0; it < n; it++) {
        int cur = it & 1;
        *(short8*)&As[cur][woffA[0]] = pA[0];
        *(short8*)&As[cur][woffA[1]] = pA[1];
        *(short8*)&Bs[cur][woffB]    = pB;
        __syncthreads();

        if (it + 1 < n) {
            int t = (it + 1) >> 4, cc = (it + 1) & 15;
            const unsigned short* Wsl =
                Wb + ((size_t)(toff[plane] + t) * C_CH + co0) * C_CH + cc * 32;
            const unsigned short* Xsl =
                Xbase + (size_t)(pos0 + t - pad + 4) * C_CH + cc * 32;
            pA[0] = *(const short8*)&Wsl[(size_t)rA0 * C_CH + sA * 8];
            pA[1] = *(const short8*)&Wsl[(size_t)(rA0 + 64) * C_CH + sA * 8];
            pB    = *(const short8*)&Xsl[(size_t)rA0 * C_CH + sA * 8];
        }

        short8 af[4], bf[2];
#pragma unroll
        for (int mi = 0; mi < 4; mi++) af[mi] = *(const short8*)&As[cur][aoff[mi]];
#pragma unroll
        for (int ni = 0; ni < 2; ni++) bf[ni] = *(const short8*)&Bs[cur][boff[ni]];
#pragma unroll
        for (int mi = 0; mi < 4; mi++)
#pragma unroll
            for (int ni = 0; ni < 2; ni++)
                acc[mi][ni] = __builtin_amdgcn_mfma_f32_16x16x32_bf16(
                    af[mi], bf[ni], acc[mi][ni], 0, 0, 0);
    }

    // epilogue via LDS: Cs[co_l][pos_l] bf16, then coalesced b128 rows out.
    __syncthreads();
    unsigned short* Cs = &As[0][0];   // 8192 shorts = 128 x 64
#pragma unroll
    for (int mi = 0; mi < 4; mi++)
#pragma unroll
        for (int r = 0; r < 4; r++) {
            int co_l = wm + mi * 16 + quad * 4 + r;
            float bv = bias[co0 + co_l];
#pragma unroll
            for (int ni = 0; ni < 2; ni++)
                Cs[co_l * 64 + wn + ni * 16 + l15] = f2bf(acc[mi][ni][r] + bv);
        }
    __syncthreads();
    {
        int co_l = tid >> 1, half = tid & 1;
        int co = co0 + co_l;
        int h = co >> 6, cl = co & 63;
        int l = cl * 16 + (pos0 >> 6);
        size_t obase =
            ((size_t)((b * 8 + h) * NP + plane) * L_SEQ + l) * DK + half * 32;
#pragma unroll
        for (int k = 0; k < 4; k++)
            *(short8*)&Out[obase + k * 8] =
                *(const short8*)&Cs[co_l * 64 + half * 32 + k * 8];
    }
}

// ---------------------------------------------------------------------------
// Stats: grouped tiles (blocks 0..39) + upper-triangle zero-fill (40..47).
// pl[((bh*16+qt)*4+j)*256 + p*64+row]. grid (48, 16 bh), 256 thr.
// ---------------------------------------------------------------------------
__global__ __launch_bounds__(256)
void attn_stats_kernel(const unsigned short* __restrict__ Qb,
                       const unsigned short* __restrict__ Kb,
                       float* __restrict__ pl, float* __restrict__ out_attn) {
    int tid = threadIdx.x;
    int bh = blockIdx.y;

    if (blockIdx.x >= 40) {   // zero-fill pair: stripes qt=z and qt=15-z (15 tiles)
        int z = blockIdx.x - 40;
        int qts[2] = {z, 15 - z};
        float4 zv = make_float4(0.f, 0.f, 0.f, 0.f);
#pragma unroll
        for (int i = 0; i < 2; i++) {
            int qt = qts[i];
            int kz = (qt + 1) * 64;
            int r = tid >> 2;
            size_t abase = ((size_t)bh * L_SEQ + qt * 64 + r) * L_SEQ;
            for (int k = kz + (tid & 3) * 4; k < L_SEQ; k += 16)
                *(float4*)&out_attn[abase + k] = zv;
        }
        return;
    }

    int qt, kt0, kt1, j, ng;
    unpack_group(blockIdx.x, qt, kt0, kt1, j, ng);
    int q0 = qt * 64;

    int b2 = bh >> 3, h2 = bh & 7;
    int plane  = b2 * 2 + (h2 >> 2);
    int b_orig = (h2 >> 1) & 1;
    int h_base = (h2 & 1) * 4;
    int w = tid >> 6, lane = tid & 63, l15 = lane & 15, quad = lane >> 4;

    const unsigned short* kbase[NP];
    short8 qa[NP][2];
#pragma unroll
    for (int p = 0; p < NP; p++) {
        size_t slice = (size_t)((b_orig * 8 + h_base + p) * NP + plane);
        kbase[p] = Kb + slice * L_SEQ * DK;
        const unsigned short* qrow =
            Qb + (slice * L_SEQ + (size_t)(q0 + w * 16 + l15)) * DK + quad * 8;
        qa[p][0] = *(const short8*)(qrow);
        qa[p][1] = *(const short8*)(qrow + 32);
    }

    float l[NP][4];
#pragma unroll
    for (int p = 0; p < NP; p++)
        for (int r = 0; r < 4; r++) l[p][r] = 0.f;

    for (int kt = kt0; kt < kt1; kt++) {
        int k0 = kt * 64;
        bool diag = (kt == qt);
#pragma unroll
        for (int p = 0; p < NP; p++) {
            f32x4 c[4];
#pragma unroll
            for (int s = 0; s < 4; s++) {
                const unsigned short* kr =
                    kbase[p] + (size_t)(k0 + s * 16 + l15) * DK + quad * 8;
                short8 kb0 = *(const short8*)(kr);
                short8 kb1 = *(const short8*)(kr + 32);
                f32x4 acc = {0.f, 0.f, 0.f, 0.f};
                acc = __builtin_amdgcn_mfma_f32_16x16x32_bf16(qa[p][0], kb0, acc, 0, 0, 0);
                acc = __builtin_amdgcn_mfma_f32_16x16x32_bf16(qa[p][1], kb1, acc, 0, 0, 0);
                c[s] = acc;
            }
#pragma unroll
            for (int r = 0; r < 4; r++) {
                int row_local = quad * 4 + r + w * 16;
#pragma unroll
                for (int s = 0; s < 4; s++) {
                    float x = c[s][r] * SC2;
                    if (diag && (s * 16 + l15 > row_local)) x = -1e30f;
                    l[p][r] += exp2f(x);
                }
            }
        }
    }

    size_t base = ((size_t)(bh * 16 + qt) * 4 + j) * 256;
#pragma unroll
    for (int p = 0; p < NP; p++)
#pragma unroll
        for (int r = 0; r < 4; r++) {
            float ll = l[p][r];
            ll += __shfl_xor(ll, 1);
            ll += __shfl_xor(ll, 2);
            ll += __shfl_xor(ll, 4);
            ll += __shfl_xor(ll, 8);
            if (l15 == 0)
                pl[base + p * 64 + (w * 16 + quad * 4 + r)] = ll;
        }
}

// ---------------------------------------------------------------------------
// Apply: grouped tiles with fused PV (R8 structure) + inlined combine (log2
// of summed pl slots). pctx[((bh*16+qt)*4+j)*4096 + qloc*64 + d].
// grid (40, 16 bh), 256 thr.
// ---------------------------------------------------------------------------
__global__ __launch_bounds__(256)
void attn_apply_kernel(const unsigned short* __restrict__ Qb,
                       const unsigned short* __restrict__ Kb,
                       const float* __restrict__ V,
                       const float* __restrict__ pl,
                       float* __restrict__ pctx, float* __restrict__ out_attn) {
    int qt, kt0, kt1, j, ng;
    unpack_group(blockIdx.x, qt, kt0, kt1, j, ng);
    int bh = blockIdx.y;
    int tid = threadIdx.x;
    int q0 = qt * 64;

    int b2 = bh >> 3, h2 = bh & 7;
    int plane  = b2 * 2 + (h2 >> 2);
    int b_orig = (h2 >> 1) & 1;
    int h_base = (h2 & 1) * 4;
    int w = tid >> 6, lane = tid & 63, l15 = lane & 15, quad = lane >> 4;

    __shared__ float zsm[NP * 64];
    __shared__ __align__(16) unsigned short ast[64 * 80];
    __shared__ __align__(16) unsigned short vts[2][64 * 80];

    // inlined combine: z = log2(sum_g pl[g])
    {
        size_t sb = ((size_t)(bh * 16 + qt) * 4) * 256 + tid;
        float lsum = pl[sb];
        for (int g = 1; g < ng; g++)
            lsum += pl[sb + (size_t)g * 256];
        zsm[tid] = __log2f(lsum);
    }

    const unsigned short* kbase[NP];
    short8 qa[NP][2];
#pragma unroll
    for (int p = 0; p < NP; p++) {
        size_t slice = (size_t)((b_orig * 8 + h_base + p) * NP + plane);
        kbase[p] = Kb + slice * L_SEQ * DK;
        const unsigned short* qrow =
            Qb + (slice * L_SEQ + (size_t)(q0 + w * 16 + l15)) * DK + quad * 8;
        qa[p][0] = *(const short8*)(qrow);
        qa[p][1] = *(const short8*)(qrow + 32);
    }

    f32x4 ctxc[4];
#pragma unroll
    for (int ds = 0; ds < 4; ds++) ctxc[ds] = (f32x4){0.f, 0.f, 0.f, 0.f};

    for (int kt = kt0; kt < kt1; kt++) {
        int k0 = kt * 64;
        bool diag = (kt == qt);
        unsigned short* vb = vts[kt & 1];

        // stage V^T tile bf16 into this kt's buffer
        {
            int kl = tid >> 2, db = (tid & 3) * 16;
            const float* vr = V + ((size_t)bh * L_SEQ + k0 + kl) * DK + db;
            float vv[16];
            *(float4*)&vv[0]  = *(const float4*)(vr);
            *(float4*)&vv[4]  = *(const float4*)(vr + 4);
            *(float4*)&vv[8]  = *(const float4*)(vr + 8);
            *(float4*)&vv[12] = *(const float4*)(vr + 12);
#pragma unroll
            for (int jj = 0; jj < 16; jj++)
                vb[(db + jj) * 80 + kl] = f2bf(vv[jj]);
        }
        __syncthreads();   // vb (and zsm on first iter) ready

        // scores -> run = max_p (s2_p - z_p)
        float run[4][4];
#pragma unroll
        for (int s = 0; s < 4; s++)
            for (int r = 0; r < 4; r++) run[s][r] = -1e30f;

#pragma unroll
        for (int p = 0; p < NP; p++) {
            f32x4 c[4];
#pragma unroll
            for (int s = 0; s < 4; s++) {
                const unsigned short* kr =
                    kbase[p] + (size_t)(k0 + s * 16 + l15) * DK + quad * 8;
                short8 kb0 = *(const short8*)(kr);
                short8 kb1 = *(const short8*)(kr + 32);
                f32x4 acc = {0.f, 0.f, 0.f, 0.f};
                acc = __builtin_amdgcn_mfma_f32_16x16x32_bf16(qa[p][0], kb0, acc, 0, 0, 0);
                acc = __builtin_amdgcn_mfma_f32_16x16x32_bf16(qa[p][1], kb1, acc, 0, 0, 0);
                c[s] = acc;
            }
#pragma unroll
            for (int r = 0; r < 4; r++) {
                float zp = zsm[p * 64 + (quad * 4 + r + w * 16)];
#pragma unroll
                for (int s = 0; s < 4; s++)
                    run[s][r] = fmaxf(run[s][r], c[s][r] * SC2 - zp);
            }
        }

        // attn write + wave-private stash
#pragma unroll
        for (int s = 0; s < 4; s++)
#pragma unroll
            for (int r = 0; r < 4; r++) {
                int qloc = w * 16 + quad * 4 + r;
                bool masked = diag && (s * 16 + l15 > qloc);
                float a = masked ? 0.f : exp2f(run[s][r]);
                out_attn[((size_t)bh * L_SEQ + q0 + qloc) * L_SEQ + k0 + s * 16 + l15] = a;
                ast[qloc * 80 + s * 16 + l15] = f2bf(a);
            }

        // PV partial into register accumulator
        short8 af0 = *(const short8*)&ast[(w * 16 + l15) * 80 + quad * 8];
        short8 af1 = *(const short8*)&ast[(w * 16 + l15) * 80 + 32 + quad * 8];
#pragma unroll
        for (int ds = 0; ds < 4; ds++) {
            short8 bf0 = *(const short8*)&vb[(ds * 16 + l15) * 80 + quad * 8];
            short8 bf1 = *(const short8*)&vb[(ds * 16 + l15) * 80 + 32 + quad * 8];
            ctxc[ds] = __builtin_amdgcn_mfma_f32_16x16x32_bf16(af0, bf0, ctxc[ds], 0, 0, 0);
            ctxc[ds] = __builtin_amdgcn_mfma_f32_16x16x32_bf16(af1, bf1, ctxc[ds], 0, 0, 0);
        }
    }

    // store the group's ctx partial (coalesced, non-atomic)
    size_t pbase = ((size_t)(bh * 16 + qt) * 4 + j) * 4096;
#pragma unroll
    for (int ds = 0; ds < 4; ds++)
#pragma unroll
        for (int r = 0; r < 4; r++) {
            int qloc = w * 16 + quad * 4 + r;
            pctx[pbase + (size_t)qloc * 64 + ds * 16 + l15] = ctxc[ds][r];
        }
}

// ---------------------------------------------------------------------------
// Reduce ctx partials: out_ctx = sum over ng slots. grid (16 qt, 16 bh).
// ---------------------------------------------------------------------------
__global__ __launch_bounds__(256)
void ctx_reduce_kernel(const float* __restrict__ pctx, float* __restrict__ out_ctx) {
    int qt = blockIdx.x, bh = blockIdx.y;
    int tid = threadIdx.x;
    int ng = (qt + 4) >> 2;
    size_t base = (size_t)(bh * 16 + qt) * 4 * 4096;
    int row = tid >> 2, c = (tid & 3) * 16;
    size_t off = (size_t)row * 64 + c;

    float4 a0 = *(const float4*)&pctx[base + off];
    float4 a1 = *(const float4*)&pctx[base + off + 4];
    float4 a2 = *(const float4*)&pctx[base + off + 8];
    float4 a3 = *(const float4*)&pctx[base + off + 12];
    for (int g = 1; g < ng; g++) {
        size_t gb = base + (size_t)g * 4096 + off;
        float4 b0 = *(const float4*)&pctx[gb];
        float4 b1 = *(const float4*)&pctx[gb + 4];
        float4 b2 = *(const float4*)&pctx[gb + 8];
        float4 b3 = *(const float4*)&pctx[gb + 12];
        a0.x += b0.x; a0.y += b0.y; a0.z += b0.z; a0.w += b0.w;
        a1.x += b1.x; a1.y += b1.y; a1.z += b1.z; a1.w += b1.w;
        a2.x += b2.x; a2.y += b2.y; a2.z += b2.z; a2.w += b2.w;
        a3.x += b3.x; a3.y += b3.y; a3.z += b3.z; a3.w += b3.w;
    }
    size_t ob = ((size_t)bh * L_SEQ + qt * 64 + row) * DK + c;
    *(float4*)&out_ctx[ob]      = a0;
    *(float4*)&out_ctx[ob + 4]  = a1;
    *(float4*)&out_ctx[ob + 8]  = a2;
    *(float4*)&out_ctx[ob + 12] = a3;
}

// ---------------------------------------------------------------------------
extern "C" void kernel_launch(void* const* d_in, const int* in_sizes, int n_in,
                              void* d_out, int out_size, void* d_ws, size_t ws_size,
                              hipStream_t stream) {
    const float* Q  = (const float*)d_in[0];
    const float* K  = (const float*)d_in[1];
    const float* V  = (const float*)d_in[2];
    const float* w0 = (const float*)d_in[4];
    const float* b0 = (const float*)d_in[5];
    const float* w1 = (const float*)d_in[6];
    const float* b1 = (const float*)d_in[7];
    const float* w2 = (const float*)d_in[8];
    const float* b2 = (const float*)d_in[9];
    const float* w3 = (const float*)d_in[10];
    const float* b3 = (const float*)d_in[11];

    char* ws = (char*)d_ws;
    unsigned short* Wb = (unsigned short*)(ws);                  // 8,388,608 B
    unsigned short* Xt = (unsigned short*)(ws + 8388608);        // 4,227,072 B
    unsigned short* Qp = (unsigned short*)(ws + 12615680);       // 8,388,608 B
    unsigned short* Kp = (unsigned short*)(ws + 21004288);       // 8,388,608 B
    float* pctx        = (float*)(ws + 29392896);                // 16,777,216 B
    // pl aliases the Wb region (dead after conv): 16*16*4*256*4 = 1 MB
    float* pl = (float*)(ws);

    float* out_ctx  = (float*)d_out;
    float* out_attn = out_ctx + 1048576;

    prep_w_kernel<<<dim3(16, 16), 256, 0, stream>>>(w0, w1, w2, w3, Wb);
    prep_x_kernel<<<dim3(16, 8, 4), 256, 0, stream>>>(Q, K, Xt);
    conv_mfma_kernel<<<dim3(1024), 256, 0, stream>>>(Xt, Wb, b0, b1, b2, b3, Qp, Kp);
    attn_stats_kernel<<<dim3(48, 16), 256, 0, stream>>>(Qp, Kp, pl, out_attn);
    attn_apply_kernel<<<dim3(40, 16), 256, 0, stream>>>(Qp, Kp, V, pl, pctx, out_attn);
    ctx_reduce_kernel<<<dim3(16, 16), 256, 0, stream>>>(pctx, out_ctx);
}